// Round 1
// baseline (181.674 us; speedup 1.0000x reference)
//
#include <hip/hip_runtime.h>

typedef __attribute__((ext_vector_type(8))) short bf16x8;
typedef __attribute__((ext_vector_type(4))) float f32x4;

#define NTOT 16384
#define MCODES 2048
#define DDIM 256

__device__ __forceinline__ unsigned short f2bf(float f) {
  union { float f; unsigned u; } v; v.f = f;
  unsigned r = v.u + 0x7FFFu + ((v.u >> 16) & 1u);   // RNE
  return (unsigned short)(r >> 16);
}
__device__ __forceinline__ float bf2f(unsigned short u) {
  union { unsigned u; float f; } v; v.u = ((unsigned)u) << 16;
  return v.f;
}

#define GLOAD16(gptr, lptr) \
  __builtin_amdgcn_global_load_lds((const __attribute__((address_space(1))) void*)(gptr), \
                                   (__attribute__((address_space(3))) void*)(lptr), 16, 0, 0)

// ---------------- prep e: bf16 convert + ||e||^2 + colmin init ----------------
// grid 512 x 256 threads; wave per row (4 rows/block)
__global__ void prep_e_k(const float* __restrict__ e, unsigned short* __restrict__ ebf,
                         float* __restrict__ esq, unsigned* __restrict__ colmin) {
  int row = blockIdx.x * 4 + (threadIdx.x >> 6);
  int lane = threadIdx.x & 63;
  const float4 v = *(const float4*)(e + (size_t)row * DDIM + lane * 4);
  ushort4 o;
  o.x = f2bf(v.x); o.y = f2bf(v.y); o.z = f2bf(v.z); o.w = f2bf(v.w);
  *(ushort4*)(ebf + (size_t)row * DDIM + lane * 4) = o;
  float s = v.x * v.x + v.y * v.y + v.z * v.z + v.w * v.w;
  #pragma unroll
  for (int off = 32; off; off >>= 1) s += __shfl_xor(s, off, 64);
  if (lane == 0) {
    esq[row] = s;
    colmin[row] = 0x7F800000u;  // +inf
  }
}

// ---------------- transpose z: (B,D,H,W) fp32 -> (N,D) bf16 ----------------
// grid (4 d-tiles, 16 hw-tiles, 16 b), 256 threads, 64x64 tile
__global__ void transpose_z_k(const float* __restrict__ z, unsigned short* __restrict__ zf) {
  __shared__ float t[64][68];
  const int b = blockIdx.z, d0 = blockIdx.x * 64, hw0 = blockIdx.y * 64;
  const int l16 = threadIdx.x & 15, g = threadIdx.x >> 4;
  const float* src = z + (size_t)b * 262144 + (size_t)d0 * 1024 + hw0;
  #pragma unroll
  for (int it = 0; it < 4; ++it) {
    int dl = it * 16 + g;
    float4 v = *(const float4*)(src + (size_t)dl * 1024 + l16 * 4);
    *(float4*)&t[dl][l16 * 4] = v;
  }
  __syncthreads();
  const int dl4 = (threadIdx.x & 15) * 4, hwl = threadIdx.x >> 4;
  unsigned short* dst = zf + ((size_t)b * 1024 + hw0) * DDIM + d0;
  #pragma unroll
  for (int it = 0; it < 4; ++it) {
    int hw = it * 16 + hwl;
    float a0 = t[dl4 + 0][hw], a1 = t[dl4 + 1][hw];
    float a2 = t[dl4 + 2][hw], a3 = t[dl4 + 3][hw];
    uint2 w;
    w.x = (unsigned)f2bf(a0) | ((unsigned)f2bf(a1) << 16);
    w.y = (unsigned)f2bf(a2) | ((unsigned)f2bf(a3) << 16);
    *(uint2*)(dst + (size_t)hw * DDIM + dl4) = w;
  }
}

// ---------------- ||z||^2 from bf16 zf ----------------
// wave per row; 4 rows/block; grid 4096
__global__ void zsq_k(const unsigned short* __restrict__ zf, float* __restrict__ zsq) {
  int row = blockIdx.x * 4 + (threadIdx.x >> 6);
  int lane = threadIdx.x & 63;
  ushort4 v = *(const ushort4*)(zf + (size_t)row * DDIM + lane * 4);
  float a = bf2f(v.x), b = bf2f(v.y), c = bf2f(v.z), d = bf2f(v.w);
  float s = a * a + b * b + c * c + d * d;
  #pragma unroll
  for (int off = 32; off; off >>= 1) s += __shfl_xor(s, off, 64);
  if (lane == 0) zsq[row] = s;
}

// ---------------- GEMM 128x128, BK=32, 4 waves (2x2), fused epilogue ----------------
__global__ __launch_bounds__(256) void gemm_k(
    const unsigned short* __restrict__ A,   // zf (N x 256) bf16
    const unsigned short* __restrict__ B,   // e  (M x 256) bf16 (B^T form)
    const float* __restrict__ zsq, const float* __restrict__ esq,
    unsigned* __restrict__ colmin, float* __restrict__ out) {
  __shared__ unsigned short As[128 * 32];
  __shared__ unsigned short Bs[128 * 32];
  const int wave = threadIdx.x >> 6, lane = threadIdx.x & 63;
  const int wm = wave >> 1, wn = wave & 1;
  const int row0 = blockIdx.y * 128, col0 = blockIdx.x * 128;

  f32x4 acc[4][4] = {};

  const int sr = wave * 16 + (lane >> 2);        // staged row 0..63
  const int sc = (lane & 3) * 8;                 // k-offset within BK
  const size_t aBase = (size_t)(row0 + sr) * DDIM + sc;
  const size_t bBase = (size_t)(col0 + sr) * DDIM + sc;

  for (int k0 = 0; k0 < DDIM; k0 += 32) {
    GLOAD16(A + aBase + k0, As + wave * 512);
    GLOAD16(A + aBase + k0 + (size_t)64 * DDIM, As + wave * 512 + 64 * 32);
    GLOAD16(B + bBase + k0, Bs + wave * 512);
    GLOAD16(B + bBase + k0 + (size_t)64 * DDIM, Bs + wave * 512 + 64 * 32);
    __syncthreads();

    bf16x8 a[4], b[4];
    #pragma unroll
    for (int i = 0; i < 4; ++i)
      a[i] = *(const bf16x8*)(As + (wm * 64 + i * 16 + (lane & 15)) * 32 + (lane >> 4) * 8);
    #pragma unroll
    for (int j = 0; j < 4; ++j)
      b[j] = *(const bf16x8*)(Bs + (wn * 64 + j * 16 + (lane & 15)) * 32 + (lane >> 4) * 8);
    #pragma unroll
    for (int i = 0; i < 4; ++i)
      #pragma unroll
      for (int j = 0; j < 4; ++j)
        acc[i][j] = __builtin_amdgcn_mfma_f32_16x16x32_bf16(a[i], b[j], acc[i][j], 0, 0, 0);
    __syncthreads();
  }

  // epilogue: dist = zsq + esq - 2*cross, clamp>=0, store + column-min
  const int r0 = lane >> 4, c = lane & 15;
  float cmin[4] = {3.4e38f, 3.4e38f, 3.4e38f, 3.4e38f};
  #pragma unroll
  for (int j = 0; j < 4; ++j) {
    const int col = col0 + wn * 64 + j * 16 + c;
    const float es = esq[col];
    #pragma unroll
    for (int i = 0; i < 4; ++i) {
      const int row = row0 + wm * 64 + i * 16 + r0 * 4;
      const float4 zs = *(const float4*)(zsq + row);
      const float d0 = fmaxf(zs.x + es - 2.0f * acc[i][j][0], 0.0f);
      const float d1 = fmaxf(zs.y + es - 2.0f * acc[i][j][1], 0.0f);
      const float d2 = fmaxf(zs.z + es - 2.0f * acc[i][j][2], 0.0f);
      const float d3 = fmaxf(zs.w + es - 2.0f * acc[i][j][3], 0.0f);
      out[(size_t)(row + 0) * MCODES + col] = d0;
      out[(size_t)(row + 1) * MCODES + col] = d1;
      out[(size_t)(row + 2) * MCODES + col] = d2;
      out[(size_t)(row + 3) * MCODES + col] = d3;
      cmin[j] = fminf(cmin[j], fminf(fminf(d0, d1), fminf(d2, d3)));
    }
  }
  #pragma unroll
  for (int j = 0; j < 4; ++j) {
    float m = cmin[j];
    m = fminf(m, __shfl_xor(m, 16, 64));
    m = fminf(m, __shfl_xor(m, 32, 64));
    if (lane < 16) {
      const int col = col0 + wn * 64 + j * 16 + lane;
      atomicMin(colmin + col, __float_as_uint(m));   // dist >= 0 -> uint order == float order
    }
  }
}

// ---------------- loss = mean(colmin) ----------------
__global__ void loss_k(const unsigned* __restrict__ colmin, float* __restrict__ loss) {
  __shared__ float sdata[4];
  int t = threadIdx.x;
  float s = 0.0f;
  for (int i = t; i < MCODES; i += 256) s += __uint_as_float(colmin[i]);
  #pragma unroll
  for (int off = 32; off; off >>= 1) s += __shfl_down(s, off, 64);
  if ((t & 63) == 0) sdata[t >> 6] = s;
  __syncthreads();
  if (t == 0) loss[0] = (sdata[0] + sdata[1] + sdata[2] + sdata[3]) * (1.0f / (float)MCODES);
}

extern "C" void kernel_launch(void* const* d_in, const int* in_sizes, int n_in,
                              void* d_out, int out_size, void* d_ws, size_t ws_size,
                              hipStream_t stream) {
  const float* z = (const float*)d_in[0];
  const float* e = (const float*)d_in[1];
  float* out = (float*)d_out;

  float* ws = (float*)d_ws;
  float* zsq = ws;                                   // 16384 f
  float* esq = ws + NTOT;                            // 2048 f
  unsigned* colmin = (unsigned*)(ws + NTOT + MCODES);// 2048 u32
  unsigned short* ebf = (unsigned short*)(ws + NTOT + 2 * MCODES);  // 1 MB
  unsigned short* zf = ebf + (size_t)MCODES * DDIM;                 // 8 MB

  prep_e_k<<<MCODES / 4, 256, 0, stream>>>(e, ebf, esq, colmin);
  transpose_z_k<<<dim3(4, 16, 16), 256, 0, stream>>>(z, zf);
  zsq_k<<<NTOT / 4, 256, 0, stream>>>(zf, zsq);
  gemm_k<<<dim3(MCODES / 128, NTOT / 128), 256, 0, stream>>>(zf, ebf, zsq, esq, colmin, out);
  loss_k<<<1, 256, 0, stream>>>(colmin, out + (size_t)NTOT * MCODES);
}